// Round 6
// baseline (445.777 us; speedup 1.0000x reference)
//
#include <hip/hip_runtime.h>
#include <hip/hip_bf16.h>
#include <math.h>

#define F_IN 256
#define F_OUT 64
#define LRELU_ALPHA 0.2f
#define EPS 1e-15f
#define CHUNK 4096           // edges per partition block
#define BSH 6                // bucket = src >> 6  (64 nodes/bucket)
#define BNODES 64
#define NBMAX 2048           // max coarse buckets (N <= 131072)
#define LCAP 2560            // per-bucket capacity (mean 2048, +11 sigma)

typedef __bf16 bf16x8 __attribute__((ext_vector_type(8)));
typedef float  f32x4  __attribute__((ext_vector_type(4)));

__device__ __forceinline__ unsigned int fkey(float x) {
    unsigned int u = __float_as_uint(x);
    return (u & 0x80000000u) ? ~u : (u | 0x80000000u);
}
__device__ __forceinline__ float funkey(unsigned int k) {
    return (k & 0x80000000u) ? __uint_as_float(k ^ 0x80000000u)
                             : __uint_as_float(~k);
}
__device__ __forceinline__ unsigned short f2bf(float x) {
    __hip_bfloat16 b = __float2bfloat16(x);
    return *reinterpret_cast<unsigned short*>(&b);
}
__device__ __forceinline__ float bf2f(unsigned short u) {
    return __uint_as_float(((unsigned int)u) << 16);
}

// ---------------------------------------------------------------------------
// K0: W prep — W[256][64] fp32 -> Wt[64][256] bf16 (transposed). One block.
// ---------------------------------------------------------------------------
__global__ __launch_bounds__(256) void wprep(
    const float* __restrict__ W, unsigned short* __restrict__ Wt)
{
    const int t = threadIdx.x;
    const int n  = t & 63;        // col
    const int kg = t >> 6;        // k-group of 64
    for (int i = 0; i < 64; ++i) {
        int k = kg * 64 + i;
        Wt[n * 256 + k] = f2bf(W[k * 64 + n]);
    }
}

// ---------------------------------------------------------------------------
// K1: MFMA bf16 GEMM (unchanged from round 5; verified).
// ---------------------------------------------------------------------------
#define KAP 72
#define KWP 264
__global__ __launch_bounds__(256) void gemm_mfma(
    const float* __restrict__ X, const unsigned short* __restrict__ Wt,
    const float* __restrict__ a,
    unsigned short* __restrict__ h_bf, float* __restrict__ s1,
    float* __restrict__ s2, unsigned int* __restrict__ gsmax, int N)
{
    __shared__ unsigned short As[128 * KAP];   // 18432 B
    __shared__ unsigned short Ws[64 * KWP];    // 33792 B
    __shared__ float red1[4], red2[4];

    const int tid  = threadIdx.x;
    const int lane = tid & 63;
    const int l15  = lane & 15;
    const int quad = lane >> 4;
    const int w    = tid >> 6;
    const int n0   = blockIdx.x * 128;

#pragma unroll
    for (int i = 0; i < 16; ++i) {
        int q  = tid + i * 256;
        int n  = q >> 6;
        int k4 = q & 63;
        *(uint2*)&Ws[n * KWP + k4 * 4] = *(const uint2*)&Wt[n * 256 + k4 * 4];
    }

    f32x4 acc[2][4] = {};

    for (int c = 0; c < 4; ++c) {
        __syncthreads();
#pragma unroll
        for (int i = 0; i < 8; ++i) {
            int q   = tid + i * 256;
            int row = q >> 4;
            int k4  = q & 15;
            int gr  = n0 + row;
            float4 v = make_float4(0.f, 0.f, 0.f, 0.f);
            if (gr < N)
                v = *(const float4*)&X[(size_t)gr * F_IN + c * 64 + k4 * 4];
            unsigned int p0 = f2bf(v.x) | ((unsigned int)f2bf(v.y) << 16);
            unsigned int p1 = f2bf(v.z) | ((unsigned int)f2bf(v.w) << 16);
            *(uint2*)&As[row * KAP + k4 * 4] = make_uint2(p0, p1);
        }
        __syncthreads();

#pragma unroll
        for (int ks = 0; ks < 64; ks += 32) {
            bf16x8 afrag[2], bfrag[4];
#pragma unroll
            for (int rt = 0; rt < 2; ++rt) {
                uint4 ua = *(const uint4*)&As[(w * 32 + rt * 16 + l15) * KAP + ks + quad * 8];
                afrag[rt] = __builtin_bit_cast(bf16x8, ua);
            }
#pragma unroll
            for (int ct = 0; ct < 4; ++ct) {
                uint4 ub = *(const uint4*)&Ws[(ct * 16 + l15) * KWP + c * 64 + ks + quad * 8];
                bfrag[ct] = __builtin_bit_cast(bf16x8, ub);
            }
#pragma unroll
            for (int rt = 0; rt < 2; ++rt)
#pragma unroll
                for (int ct = 0; ct < 4; ++ct)
                    acc[rt][ct] = __builtin_amdgcn_mfma_f32_16x16x32_bf16(
                        afrag[rt], bfrag[ct], acc[rt][ct], 0, 0, 0);
        }
    }

    float a1v[4], a2v[4];
#pragma unroll
    for (int ct = 0; ct < 4; ++ct) {
        a1v[ct] = a[ct * 16 + l15];
        a2v[ct] = a[F_OUT + ct * 16 + l15];
    }
    float m1 = -INFINITY, m2 = -INFINITY;
#pragma unroll
    for (int rt = 0; rt < 2; ++rt) {
#pragma unroll
        for (int reg = 0; reg < 4; ++reg) {
            int n = n0 + w * 32 + rt * 16 + quad * 4 + reg;
            float p1 = 0.f, p2 = 0.f;
#pragma unroll
            for (int ct = 0; ct < 4; ++ct) {
                float v = acc[rt][ct][reg];
                p1 = fmaf(v, a1v[ct], p1);
                p2 = fmaf(v, a2v[ct], p2);
            }
#pragma unroll
            for (int ofs = 1; ofs < 16; ofs <<= 1) {
                p1 += __shfl_xor(p1, ofs, 64);
                p2 += __shfl_xor(p2, ofs, 64);
            }
            if (n < N) {
#pragma unroll
                for (int ct = 0; ct < 4; ++ct)
                    h_bf[(size_t)n * F_OUT + ct * 16 + l15] = f2bf(acc[rt][ct][reg]);
                if (l15 == 0) { s1[n] = p1; s2[n] = p2; }
                m1 = fmaxf(m1, p1);
                m2 = fmaxf(m2, p2);
            }
        }
    }
#pragma unroll
    for (int ofs = 32; ofs > 0; ofs >>= 1) {
        m1 = fmaxf(m1, __shfl_xor(m1, ofs, 64));
        m2 = fmaxf(m2, __shfl_xor(m2, ofs, 64));
    }
    if (lane == 0) { red1[w] = m1; red2[w] = m2; }
    __syncthreads();
    if (tid == 0) {
        float b1 = fmaxf(fmaxf(red1[0], red1[1]), fmaxf(red1[2], red1[3]));
        float b2 = fmaxf(fmaxf(red2[0], red2[1]), fmaxf(red2[2], red2[3]));
        atomicMax(&gsmax[0], fkey(b1));
        atomicMax(&gsmax[1], fkey(b2));
    }
}

// ---------------------------------------------------------------------------
// K2: coarse partition into 64-node buckets (bucket = src>>6). Block-local
// LDS histogram -> one global atomicAdd per (block,bucket) -> dense append of
// packed (dst<<6 | src&63). Moving fronts keep HBM writeback ~= payload.
// ---------------------------------------------------------------------------
__global__ __launch_bounds__(256) void partition_edges(
    const int* __restrict__ src, const int* __restrict__ dst,
    int* __restrict__ coarse_cnt, unsigned int* __restrict__ coarse,
    int E, int NB)
{
    __shared__ int hist[NBMAX];
    __shared__ int cur[NBMAX];
    const int e0 = blockIdx.x * CHUNK;
    const int e1 = (e0 + CHUNK < E) ? e0 + CHUNK : E;

    for (int i = threadIdx.x; i < NB; i += 256) hist[i] = 0;
    __syncthreads();
    for (int e = e0 + threadIdx.x; e < e1; e += 256)
        atomicAdd(&hist[src[e] >> BSH], 1);
    __syncthreads();
    for (int i = threadIdx.x; i < NB; i += 256) {
        int c = hist[i];
        cur[i] = c ? atomicAdd(&coarse_cnt[i], c) : 0;
    }
    __syncthreads();
    for (int e = e0 + threadIdx.x; e < e1; e += 256) {
        int s = src[e], d = dst[e];
        int b = s >> BSH;
        int pos = atomicAdd(&cur[b], 1);
        if (pos < LCAP)
            coarse[(size_t)b * LCAP + pos] =
                ((unsigned int)d << BSH) | (unsigned int)(s & (BNODES - 1));
    }
}

// ---------------------------------------------------------------------------
// K3: merged fine-bin + gather. One workgroup per 64-node bucket.
// Phase A: LDS histogram of local src. Phase B: LDS scan -> row starts.
// Phase C: compute w = exp(lrelu(s1[src]+s2[dst]) - M) (s1 slice staged in
// LDS, s2 gathered), scatter (dst<<15 | bf16bits(w)) into LDS CSR.
// Phase D: per-node gather of h rows, 2 edges per wave-instr (lanes 0-31 =
// edge k, 32-63 = edge k+1; dword = 2 bf16 features per lane), fp32 accum,
// fused softmax-normalize + ELU, float2 store. No global CSR, no fp atomics.
// ---------------------------------------------------------------------------
__global__ __launch_bounds__(256) void bin_gather(
    const unsigned int* __restrict__ coarse, const int* __restrict__ coarse_cnt,
    const float* __restrict__ s1, const float* __restrict__ s2,
    const unsigned int* __restrict__ gsmax,
    const unsigned short* __restrict__ hb, float* __restrict__ out, int N)
{
    __shared__ unsigned int leds[LCAP];      // 10240 B
    __shared__ int   hcnt[BNODES];
    __shared__ int   hinc[BNODES];           // inclusive scan
    __shared__ int   curs[BNODES];
    __shared__ float s1s[BNODES];

    const int b  = blockIdx.x;
    const int t  = threadIdx.x;
    const int n0 = b << BSH;
    int cnt = coarse_cnt[b];
    if (cnt > LCAP) cnt = LCAP;
    const unsigned int* cb = coarse + (size_t)b * LCAP;

    if (t < BNODES) {
        hcnt[t] = 0;
        s1s[t] = (n0 + t < N) ? s1[n0 + t] : 0.f;
    }
    __syncthreads();

    // Phase A: histogram
    for (int e = t; e < cnt; e += 256)
        atomicAdd(&hcnt[cb[e] & (BNODES - 1)], 1);
    __syncthreads();

    // Phase B: inclusive scan over BNODES counters
    if (t < BNODES) hinc[t] = hcnt[t];
    __syncthreads();
    for (int d = 1; d < BNODES; d <<= 1) {
        int x = (t < BNODES && t >= d) ? hinc[t - d] : 0;
        __syncthreads();
        if (t < BNODES) hinc[t] += x;
        __syncthreads();
    }
    if (t < BNODES) curs[t] = hinc[t] - hcnt[t];   // exclusive start
    __syncthreads();

    // Phase C: weights + LDS scatter
    const float M = funkey(gsmax[0]) + funkey(gsmax[1]);
    for (int e = t; e < cnt; e += 256) {
        unsigned int p = cb[e];
        int sl = p & (BNODES - 1);
        int d  = p >> BSH;
        float v = s1s[sl] + s2[d];
        v = (v >= 0.f) ? v : LRELU_ALPHA * v;
        float w = __expf(v - M);               // in (0,1]
        unsigned int wb = f2bf(w);             // sign=0 -> 15 bits
        int pos = atomicAdd(&curs[sl], 1);
        leds[pos] = ((unsigned int)d << 15) | wb;
    }
    __syncthreads();

    // Phase D: gather. Wave wv handles local nodes [wv*16, wv*16+16).
    const int lane = t & 63;
    const int wv   = t >> 6;
    const int hm   = lane & 31;                // feature pair index

    for (int nl = wv * 16; nl < wv * 16 + 16; ++nl) {
        const int n = n0 + nl;
        if (n >= N) break;
        const int re = hinc[nl];
        const int rs = re - hcnt[nl];

        float ax = 0.f, ay = 0.f, wsum_l = 0.f;
        for (int bb = rs; bb < re; bb += 64) {
            const int nb = (re - bb < 64) ? re - bb : 64;
            unsigned int pv = (lane < nb) ? leds[bb + lane] : 0u;
            wsum_l += bf2f((unsigned short)(pv & 0x7fffu));
            for (int k = 0; k < nb; k += 2) {
                int idx = k + (lane >> 5);                 // <=63; pv=0 pad
                unsigned int pe = __shfl(pv, idx, 64);
                int   d = pe >> 15;
                float w = bf2f((unsigned short)(pe & 0x7fffu));
                unsigned int hv = *(const unsigned int*)&hb[(size_t)d * F_OUT + hm * 2];
                ax = fmaf(w, bf2f((unsigned short)(hv & 0xffffu)), ax);
                ay = fmaf(w, bf2f((unsigned short)(hv >> 16)), ay);
            }
        }
        // merge halves + full weight sum
        ax += __shfl_xor(ax, 32, 64);
        ay += __shfl_xor(ay, 32, 64);
#pragma unroll
        for (int ofs = 32; ofs > 0; ofs >>= 1)
            wsum_l += __shfl_xor(wsum_l, ofs, 64);

        float inv = 1.f / (wsum_l + EPS);
        float x0 = ax * inv, x1 = ay * inv;
        x0 = (x0 > 0.f) ? x0 : expm1f(x0);
        x1 = (x1 > 0.f) ? x1 : expm1f(x1);
        if (lane < 32)
            *(float2*)&out[(size_t)n * F_OUT + hm * 2] = make_float2(x0, x1);
    }
}

extern "C" void kernel_launch(void* const* d_in, const int* in_sizes, int n_in,
                              void* d_out, int out_size, void* d_ws, size_t ws_size,
                              hipStream_t stream) {
    const float* X   = (const float*)d_in[0];
    const int*   ei  = (const int*)d_in[1];
    const float* W   = (const float*)d_in[2];
    const float* a   = (const float*)d_in[3];
    float*       out = (float*)d_out;

    const int N = in_sizes[0] / F_IN;     // 100000
    const int E = in_sizes[1] / 2;        // 3200000
    const int* src = ei;
    const int* dst = ei + E;

    const int NB = (N + BNODES - 1) >> BSH;          // 1563 buckets

    // workspace layout (~30 MB)
    unsigned short* h_bf = (unsigned short*)d_ws;            // N*64 bf16
    float* s1         = (float*)(h_bf + (size_t)N * F_OUT);  // N
    float* s2         = s1 + N;                              // N
    int*   coarse_cnt = (int*)(s2 + N);                      // NB
    unsigned int* gsmax = (unsigned int*)(coarse_cnt + NB);  // 2 (contiguous)
    unsigned short* Wt = (unsigned short*)(gsmax + 2);       // 64*256 bf16
    unsigned int* coarse = (unsigned int*)(Wt + 64 * 256);   // NB*LCAP

    // zero coarse_cnt + gsmax in one memset
    hipMemsetAsync(coarse_cnt, 0, ((size_t)NB + 2) * sizeof(int), stream);

    wprep          <<<1, 256, 0, stream>>>(W, Wt);
    gemm_mfma      <<<(N + 127) / 128, 256, 0, stream>>>(X, Wt, a, h_bf, s1, s2,
                                                         gsmax, N);
    partition_edges<<<(E + CHUNK - 1) / CHUNK, 256, 0, stream>>>(src, dst, coarse_cnt,
                                                                 coarse, E, NB);
    bin_gather     <<<NB, 256, 0, stream>>>(coarse, coarse_cnt, s1, s2, gsmax,
                                            h_bf, out, N);
}

// Round 7
// 366.432 us; speedup vs baseline: 1.2165x; 1.2165x over previous
//
#include <hip/hip_runtime.h>
#include <hip/hip_bf16.h>
#include <math.h>

#define F_IN 256
#define F_OUT 64
#define LRELU_ALPHA 0.2f
#define EPS 1e-15f
#define CHUNK 8192           // edges per partition block
#define BSH 7                // bucket = src >> 7  (128 nodes/bucket)
#define BNODES 128
#define NBMAX 1024           // max coarse buckets (N <= 131072)
#define LCAP 4800            // per-bucket cap (mean 4096, +11 sigma)

typedef __bf16 bf16x8 __attribute__((ext_vector_type(8)));
typedef float  f32x4  __attribute__((ext_vector_type(4)));

__device__ __forceinline__ unsigned int fkey(float x) {
    unsigned int u = __float_as_uint(x);
    return (u & 0x80000000u) ? ~u : (u | 0x80000000u);
}
__device__ __forceinline__ float funkey(unsigned int k) {
    return (k & 0x80000000u) ? __uint_as_float(k ^ 0x80000000u)
                             : __uint_as_float(~k);
}
__device__ __forceinline__ unsigned short f2bf(float x) {
    __hip_bfloat16 b = __float2bfloat16(x);
    return *reinterpret_cast<unsigned short*>(&b);
}
__device__ __forceinline__ float bf2f(unsigned int u) {
    return __uint_as_float(u << 16);
}

// ---------------------------------------------------------------------------
// K0: W prep — W[256][64] fp32 -> Wt[64][256] bf16 (transposed). One block.
// Must precede the fused kernel (gemm blocks read Wt).
// ---------------------------------------------------------------------------
__global__ __launch_bounds__(256) void wprep(
    const float* __restrict__ W, unsigned short* __restrict__ Wt)
{
    const int t = threadIdx.x;
    const int n  = t & 63;
    const int kg = t >> 6;
    for (int i = 0; i < 64; ++i) {
        int k = kg * 64 + i;
        Wt[n * 256 + k] = f2bf(W[k * 64 + n]);
    }
}

// ---------------------------------------------------------------------------
// K1: FUSED gemm+partition. Blocks [0, GB): MFMA bf16 GEMM tile (verified
// round-5 body). Blocks [GB, GB+PB): coarse edge partition into 128-node
// buckets. No data dependency between the halves -> they co-schedule,
// total ~= max(gemm, partition) instead of sum.
// ---------------------------------------------------------------------------
#define KAP 72
#define KWP 264
__global__ __launch_bounds__(256) void gemm_part(
    const float* __restrict__ X, const unsigned short* __restrict__ Wt,
    const float* __restrict__ a,
    unsigned short* __restrict__ h_bf, float* __restrict__ s1,
    float* __restrict__ s2, unsigned int* __restrict__ gsmax, int N,
    const int* __restrict__ src, const int* __restrict__ dst,
    int* __restrict__ coarse_cnt, unsigned int* __restrict__ coarse,
    int E, int NB, int GB)
{
    __shared__ __align__(16) char smem[52256];

    if (blockIdx.x < GB) {
        // ---------------- GEMM branch ----------------
        unsigned short* As  = (unsigned short*)smem;            // 128*KAP
        unsigned short* Ws  = (unsigned short*)(smem + 18432);  // 64*KWP
        float* red1 = (float*)(smem + 52224);                   // 4
        float* red2 = red1 + 4;                                 // 4

        const int tid  = threadIdx.x;
        const int lane = tid & 63;
        const int l15  = lane & 15;
        const int quad = lane >> 4;
        const int w    = tid >> 6;
        const int n0   = blockIdx.x * 128;

#pragma unroll
        for (int i = 0; i < 16; ++i) {
            int q  = tid + i * 256;
            int n  = q >> 6;
            int k4 = q & 63;
            *(uint2*)&Ws[n * KWP + k4 * 4] = *(const uint2*)&Wt[n * 256 + k4 * 4];
        }

        f32x4 acc[2][4] = {};

        for (int c = 0; c < 4; ++c) {
            __syncthreads();
#pragma unroll
            for (int i = 0; i < 8; ++i) {
                int q   = tid + i * 256;
                int row = q >> 4;
                int k4  = q & 15;
                int gr  = n0 + row;
                float4 v = make_float4(0.f, 0.f, 0.f, 0.f);
                if (gr < N)
                    v = *(const float4*)&X[(size_t)gr * F_IN + c * 64 + k4 * 4];
                unsigned int p0 = f2bf(v.x) | ((unsigned int)f2bf(v.y) << 16);
                unsigned int p1 = f2bf(v.z) | ((unsigned int)f2bf(v.w) << 16);
                *(uint2*)&As[row * KAP + k4 * 4] = make_uint2(p0, p1);
            }
            __syncthreads();

#pragma unroll
            for (int ks = 0; ks < 64; ks += 32) {
                bf16x8 afrag[2], bfrag[4];
#pragma unroll
                for (int rt = 0; rt < 2; ++rt) {
                    uint4 ua = *(const uint4*)&As[(w * 32 + rt * 16 + l15) * KAP + ks + quad * 8];
                    afrag[rt] = __builtin_bit_cast(bf16x8, ua);
                }
#pragma unroll
                for (int ct = 0; ct < 4; ++ct) {
                    uint4 ub = *(const uint4*)&Ws[(ct * 16 + l15) * KWP + c * 64 + ks + quad * 8];
                    bfrag[ct] = __builtin_bit_cast(bf16x8, ub);
                }
#pragma unroll
                for (int rt = 0; rt < 2; ++rt)
#pragma unroll
                    for (int ct = 0; ct < 4; ++ct)
                        acc[rt][ct] = __builtin_amdgcn_mfma_f32_16x16x32_bf16(
                            afrag[rt], bfrag[ct], acc[rt][ct], 0, 0, 0);
            }
        }

        float a1v[4], a2v[4];
#pragma unroll
        for (int ct = 0; ct < 4; ++ct) {
            a1v[ct] = a[ct * 16 + l15];
            a2v[ct] = a[F_OUT + ct * 16 + l15];
        }
        float m1 = -INFINITY, m2 = -INFINITY;
#pragma unroll
        for (int rt = 0; rt < 2; ++rt) {
#pragma unroll
            for (int reg = 0; reg < 4; ++reg) {
                int n = n0 + w * 32 + rt * 16 + quad * 4 + reg;
                float p1 = 0.f, p2 = 0.f;
#pragma unroll
                for (int ct = 0; ct < 4; ++ct) {
                    float v = acc[rt][ct][reg];
                    p1 = fmaf(v, a1v[ct], p1);
                    p2 = fmaf(v, a2v[ct], p2);
                }
#pragma unroll
                for (int ofs = 1; ofs < 16; ofs <<= 1) {
                    p1 += __shfl_xor(p1, ofs, 64);
                    p2 += __shfl_xor(p2, ofs, 64);
                }
                if (n < N) {
#pragma unroll
                    for (int ct = 0; ct < 4; ++ct)
                        h_bf[(size_t)n * F_OUT + ct * 16 + l15] = f2bf(acc[rt][ct][reg]);
                    if (l15 == 0) { s1[n] = p1; s2[n] = p2; }
                    m1 = fmaxf(m1, p1);
                    m2 = fmaxf(m2, p2);
                }
            }
        }
#pragma unroll
        for (int ofs = 32; ofs > 0; ofs >>= 1) {
            m1 = fmaxf(m1, __shfl_xor(m1, ofs, 64));
            m2 = fmaxf(m2, __shfl_xor(m2, ofs, 64));
        }
        if (lane == 0) { red1[w] = m1; red2[w] = m2; }
        __syncthreads();
        if (tid == 0) {
            float b1 = fmaxf(fmaxf(red1[0], red1[1]), fmaxf(red1[2], red1[3]));
            float b2 = fmaxf(fmaxf(red2[0], red2[1]), fmaxf(red2[2], red2[3]));
            atomicMax(&gsmax[0], fkey(b1));
            atomicMax(&gsmax[1], fkey(b2));
        }
    } else {
        // ---------------- partition branch ----------------
        int* hist = (int*)smem;          // NBMAX
        int* cur  = hist + NBMAX;        // NBMAX
        const int pb = blockIdx.x - GB;
        const int e0 = pb * CHUNK;
        const int e1 = (e0 + CHUNK < E) ? e0 + CHUNK : E;

        for (int i = threadIdx.x; i < NB; i += 256) hist[i] = 0;
        __syncthreads();
        for (int e = e0 + threadIdx.x; e < e1; e += 256)
            atomicAdd(&hist[src[e] >> BSH], 1);
        __syncthreads();
        for (int i = threadIdx.x; i < NB; i += 256) {
            int c = hist[i];
            cur[i] = c ? atomicAdd(&coarse_cnt[i], c) : 0;
        }
        __syncthreads();
        for (int e = e0 + threadIdx.x; e < e1; e += 256) {
            int s = src[e], d = dst[e];
            int b = s >> BSH;
            int pos = atomicAdd(&cur[b], 1);
            if (pos < LCAP)
                coarse[(size_t)b * LCAP + pos] =
                    ((unsigned int)d << BSH) | (unsigned int)(s & (BNODES - 1));
        }
    }
}

// ---------------------------------------------------------------------------
// K2: merged fine-bin + gather, 512 threads per 128-node bucket.
// A: LDS histogram.  B: LDS scan -> row starts.  C: w = exp(lrelu(s1+s2)-M)
// (s1 slice in LDS, s2 gathered), scatter (dst<<15 | bf16(w)) into LDS CSR.
// D: one node per HALF-WAVE (32 lanes x dword = full 128B h-row per instr,
// 2 edges per wave-instr), 4-wide unrolled shfl+load for ILP, fp32 accum,
// fused softmax-normalize + ELU, float2 stores.
// ---------------------------------------------------------------------------
__global__ __launch_bounds__(512) void bin_gather(
    const unsigned int* __restrict__ coarse, const int* __restrict__ coarse_cnt,
    const float* __restrict__ s1, const float* __restrict__ s2,
    const unsigned int* __restrict__ gsmax,
    const unsigned short* __restrict__ hb, float* __restrict__ out, int N)
{
    __shared__ unsigned int leds[LCAP];      // 19200 B
    __shared__ int   hcnt[BNODES];
    __shared__ int   hinc[BNODES];
    __shared__ int   curs[BNODES];
    __shared__ float s1s[BNODES];

    const int b  = blockIdx.x;
    const int t  = threadIdx.x;
    const int n0 = b << BSH;
    int cnt = coarse_cnt[b];
    if (cnt > LCAP) cnt = LCAP;
    const unsigned int* cb = coarse + (size_t)b * LCAP;

    if (t < BNODES) {
        hcnt[t] = 0;
        s1s[t] = (n0 + t < N) ? s1[n0 + t] : 0.f;
    }
    __syncthreads();

    // Phase A: histogram of local src
    for (int e = t; e < cnt; e += 512)
        atomicAdd(&hcnt[cb[e] & (BNODES - 1)], 1);
    __syncthreads();

    // Phase B: inclusive scan over BNODES counters
    if (t < BNODES) hinc[t] = hcnt[t];
    __syncthreads();
    for (int d = 1; d < BNODES; d <<= 1) {
        int x = (t < BNODES && t >= d) ? hinc[t - d] : 0;
        __syncthreads();
        if (t < BNODES) hinc[t] += x;
        __syncthreads();
    }
    if (t < BNODES) curs[t] = hinc[t] - hcnt[t];
    __syncthreads();

    // Phase C: weights + LDS scatter
    const float M = funkey(gsmax[0]) + funkey(gsmax[1]);
    for (int e = t; e < cnt; e += 512) {
        unsigned int p = cb[e];
        int sl = p & (BNODES - 1);
        int d  = p >> BSH;
        float v = s1s[sl] + s2[d];
        v = fmaxf(v, LRELU_ALPHA * v);          // leaky-relu
        float w = __expf(v - M);                // in (0,1]
        unsigned int wb = f2bf(w);              // sign=0 -> 15 bits
        int pos = atomicAdd(&curs[sl], 1);
        leds[pos] = ((unsigned int)d << 15) | wb;
    }
    __syncthreads();

    // Phase D: gather. Half-wave hw handles nodes [hw*8, hw*8+8).
    const int lane  = t & 63;
    const int fl    = lane & 31;                // feature-pair index / edge slot
    const int sbase = lane & 32;                // shfl base for own half
    const int hw    = ((t >> 6) << 1) | (lane >> 5);   // 0..15

    for (int i = 0; i < 8; ++i) {
        const int nl = hw * 8 + i;
        const int n  = n0 + nl;
        const bool valid = (n < N);
        const int re = valid ? hinc[nl] : 0;
        const int rs = valid ? re - hcnt[nl] : 0;

        float ax = 0.f, ay = 0.f, ws = 0.f;
        for (int bb = rs; bb < re; bb += 32) {
            const int nb = (re - bb < 32) ? re - bb : 32;
            unsigned int pv = (fl < nb) ? leds[bb + fl] : 0u;
            ws += bf2f(pv & 0x7fffu);
            int k = 0;
            for (; k + 4 <= nb; k += 4) {
                unsigned int pe0 = __shfl(pv, sbase | (k + 0), 64);
                unsigned int pe1 = __shfl(pv, sbase | (k + 1), 64);
                unsigned int pe2 = __shfl(pv, sbase | (k + 2), 64);
                unsigned int pe3 = __shfl(pv, sbase | (k + 3), 64);
                unsigned int hv0 = *(const unsigned int*)&hb[(size_t)(pe0 >> 15) * F_OUT + fl * 2];
                unsigned int hv1 = *(const unsigned int*)&hb[(size_t)(pe1 >> 15) * F_OUT + fl * 2];
                unsigned int hv2 = *(const unsigned int*)&hb[(size_t)(pe2 >> 15) * F_OUT + fl * 2];
                unsigned int hv3 = *(const unsigned int*)&hb[(size_t)(pe3 >> 15) * F_OUT + fl * 2];
                float w0 = bf2f(pe0 & 0x7fffu);
                float w1 = bf2f(pe1 & 0x7fffu);
                float w2 = bf2f(pe2 & 0x7fffu);
                float w3 = bf2f(pe3 & 0x7fffu);
                ax = fmaf(w0, bf2f(hv0 & 0xffffu), ax);
                ay = fmaf(w0, bf2f(hv0 >> 16), ay);
                ax = fmaf(w1, bf2f(hv1 & 0xffffu), ax);
                ay = fmaf(w1, bf2f(hv1 >> 16), ay);
                ax = fmaf(w2, bf2f(hv2 & 0xffffu), ax);
                ay = fmaf(w2, bf2f(hv2 >> 16), ay);
                ax = fmaf(w3, bf2f(hv3 & 0xffffu), ax);
                ay = fmaf(w3, bf2f(hv3 >> 16), ay);
            }
            for (; k < nb; ++k) {
                unsigned int pe = __shfl(pv, sbase | k, 64);
                unsigned int hv = *(const unsigned int*)&hb[(size_t)(pe >> 15) * F_OUT + fl * 2];
                float w = bf2f(pe & 0x7fffu);
                ax = fmaf(w, bf2f(hv & 0xffffu), ax);
                ay = fmaf(w, bf2f(hv >> 16), ay);
            }
        }
        // weight sum within the half (ofs 1..16 stay inside 32-lane half)
#pragma unroll
        for (int ofs = 1; ofs <= 16; ofs <<= 1)
            ws += __shfl_xor(ws, ofs, 64);

        if (valid) {
            float inv = 1.f / (ws + EPS);
            float x0 = ax * inv, x1 = ay * inv;
            x0 = (x0 > 0.f) ? x0 : expm1f(x0);
            x1 = (x1 > 0.f) ? x1 : expm1f(x1);
            *(float2*)&out[(size_t)n * F_OUT + fl * 2] = make_float2(x0, x1);
        }
    }
}

extern "C" void kernel_launch(void* const* d_in, const int* in_sizes, int n_in,
                              void* d_out, int out_size, void* d_ws, size_t ws_size,
                              hipStream_t stream) {
    const float* X   = (const float*)d_in[0];
    const int*   ei  = (const int*)d_in[1];
    const float* W   = (const float*)d_in[2];
    const float* a   = (const float*)d_in[3];
    float*       out = (float*)d_out;

    const int N = in_sizes[0] / F_IN;     // 100000
    const int E = in_sizes[1] / 2;        // 3200000
    const int* src = ei;
    const int* dst = ei + E;

    const int NB = (N + BNODES - 1) >> BSH;          // 782 buckets
    const int GB = (N + 127) / 128;                  // 782 gemm blocks
    const int PB = (E + CHUNK - 1) / CHUNK;          // 391 partition blocks

    // workspace layout (~29 MB)
    unsigned short* h_bf = (unsigned short*)d_ws;            // N*64 bf16
    float* s1         = (float*)(h_bf + (size_t)N * F_OUT);  // N
    float* s2         = s1 + N;                              // N
    int*   coarse_cnt = (int*)(s2 + N);                      // NB
    unsigned int* gsmax = (unsigned int*)(coarse_cnt + NB);  // 2 (contiguous)
    unsigned short* Wt = (unsigned short*)(gsmax + 2);       // 64*256 bf16
    unsigned int* coarse = (unsigned int*)(Wt + 64 * 256);   // NB*LCAP

    // zero coarse_cnt + gsmax in one memset
    hipMemsetAsync(coarse_cnt, 0, ((size_t)NB + 2) * sizeof(int), stream);

    wprep     <<<1, 256, 0, stream>>>(W, Wt);
    gemm_part <<<GB + PB, 256, 0, stream>>>(X, Wt, a, h_bf, s1, s2, gsmax, N,
                                            src, dst, coarse_cnt, coarse,
                                            E, NB, GB);
    bin_gather<<<NB, 512, 0, stream>>>(coarse, coarse_cnt, s1, s2, gsmax,
                                       h_bf, out, N);
}